// Round 11
// baseline (187.970 us; speedup 1.0000x reference)
//
#include <hip/hip_runtime.h>
#include <hip/hip_bf16.h>

// ROUND 20: (1) attn: correct-order v_permlane32_swap replaces shfl_xor —
// R18 vs R19 differential proves the instruction swaps first.upper <->
// second.lower, so pl32swap(w0,w2)/pl32swap(w1,w3) builds the PV A-frag
// words in place (pure VALU; kills the 1.6M ds_bpermute bank conflicts and
// 16 cross-lane latencies/tile that made R19 neutral).
// (2) gemm_proj widened to 128x128 tile (16 MFMA/K-step, clone of the
// proven gemm_qkv_bf16 loop, plain f32 epilogue, grid 32x8) — timing
// arithmetic puts the old 128x64 version at ~35-40us / ~200 TF.
// Everything else identical to R19 (passing).

typedef __attribute__((ext_vector_type(8))) short bf16x8;
typedef __attribute__((ext_vector_type(4))) short bf16x4;
typedef __attribute__((ext_vector_type(4))) float floatx4;
typedef __attribute__((ext_vector_type(16))) float f32x16;

#define MFMA16(a, b, c) __builtin_amdgcn_mfma_f32_16x16x32_bf16((a), (b), (c), 0, 0, 0)
#define MFMA32(a, b, c) __builtin_amdgcn_mfma_f32_32x32x16_bf16((a), (b), (c), 0, 0, 0)

#if __has_builtin(__builtin_amdgcn_exp2f)
#define EXP2F(x) __builtin_amdgcn_exp2f(x)
#else
#define EXP2F(x) exp2f(x)
#endif

static constexpr int Bc = 2, Tc = 2048, Cc = 1024, Hc = 16, Dc = 64;
static constexpr size_t QKV_STRIDE = (size_t)Bc * Hc * Tc * Dc; // 4194304
static constexpr float KSL2E = 0.125f * 1.44269504088896f; // scale * log2(e)

__device__ __forceinline__ bf16x8 load8(const __hip_bfloat16* p) {
    return *(const bf16x8*)p;
}

__device__ __forceinline__ short f2b(float x) {
    union { __hip_bfloat16 h; short s; } u;
    u.h = __float2bfloat16(x);
    return u.s;
}

__device__ __forceinline__ bf16x8 pack8(floatx4 a, floatx4 b) {
    bf16x8 r;
    r[0] = f2b(a[0]); r[1] = f2b(a[1]); r[2] = f2b(a[2]); r[3] = f2b(a[3]);
    r[4] = f2b(b[0]); r[5] = f2b(b[1]); r[6] = f2b(b[2]); r[7] = f2b(b[3]);
    return r;
}

// pack 2 f32 -> u32 of 2 bf16 (lo = a, hi = b); compiler emits cvt_pk
__device__ __forceinline__ unsigned pk2(float a, float b) {
    return (unsigned)(unsigned short)f2b(a) |
           ((unsigned)(unsigned short)f2b(b) << 16);
}

// v_permlane32_swap_b32 a, b: a.lanes[32+i] <-> b.lanes[i]  (proven R18/R19)
__device__ __forceinline__ void pl32swap(unsigned& a, unsigned& b) {
    asm volatile("v_permlane32_swap_b32 %0, %1" : "+v"(a), "+v"(b));
}

__device__ __forceinline__ bf16x8 mk8(unsigned a, unsigned b, unsigned c, unsigned d) {
    union { unsigned u[4]; bf16x8 v; } x;
    x.u[0] = a; x.u[1] = b; x.u[2] = c; x.u[3] = d;
    return x.v;
}

__device__ __forceinline__ void gl2lds16(const void* g, void* l) {
    __builtin_amdgcn_global_load_lds(
        (const __attribute__((address_space(1))) void*)g,
        (__attribute__((address_space(3))) void*)l, 16, 0, 0);
}

// ================= f32 -> bf16 bulk convert (8 elems/thread) ================
__global__ __launch_bounds__(256) void cvt_bf16(
    const float* __restrict__ in, __hip_bfloat16* __restrict__ out, int n8) {
    const int i = blockIdx.x * 256 + threadIdx.x;
    if (i < n8) {
        const floatx4 a = *(const floatx4*)&in[(size_t)i * 8];
        const floatx4 b = *(const floatx4*)&in[(size_t)i * 8 + 4];
        *(bf16x8*)&out[(size_t)i * 8] = pack8(a, b);
    }
}

// ================= GEMM1 bf16 (R14): qkv = xb @ wb^T ========================
__global__ __launch_bounds__(256) void gemm_qkv_bf16(
    const __hip_bfloat16* __restrict__ A,
    const __hip_bfloat16* __restrict__ W,
    __hip_bfloat16* __restrict__ qkv) {
    __shared__ __hip_bfloat16 As16[128 * 32];
    __shared__ __hip_bfloat16 Bs16[128 * 32];
    const int K = Cc;
    const int lane = threadIdx.x & 63;
    const int wave = threadIdx.x >> 6;
    const int waveM = wave >> 1, waveN = wave & 1;
    const int mBase = blockIdx.x * 128;
    const int nBase = blockIdx.y * 128;
    const int idx16 = lane & 15;
    const int quad = lane >> 4;
    const int aRow = lane >> 2, aPos = lane & 3;

    floatx4 acc[4][4] = {};

    for (int k0 = 0; k0 < K; k0 += 32) {
        __syncthreads();
#pragma unroll
        for (int s = 0; s < 2; s++) {
            const int r0 = wave * 32 + s * 16;
            const int row = r0 + aRow;
            const int cg = aPos ^ (row & 3);
            gl2lds16(A + (size_t)(mBase + row) * K + k0 + cg * 8, &As16[r0 * 32]);
            gl2lds16(W + (size_t)(nBase + row) * K + k0 + cg * 8, &Bs16[r0 * 32]);
        }
        __syncthreads();

        bf16x8 af[4], bfr[4];
#pragma unroll
        for (int i = 0; i < 4; i++) {
            const int rr = waveM * 64 + i * 16 + idx16;
            af[i] = *(const bf16x8*)&As16[rr * 32 + ((quad ^ (rr & 3)) * 8)];
        }
#pragma unroll
        for (int j = 0; j < 4; j++) {
            const int rr = waveN * 64 + j * 16 + idx16;
            bfr[j] = *(const bf16x8*)&Bs16[rr * 32 + ((quad ^ (rr & 3)) * 8)];
        }
#pragma unroll
        for (int i = 0; i < 4; i++)
#pragma unroll
            for (int j = 0; j < 4; j++)
                acc[i][j] = MFMA16(af[i], bfr[j], acc[i][j]);
    }

#pragma unroll
    for (int i = 0; i < 4; i++) {
#pragma unroll
        for (int j = 0; j < 4; j++) {
            const int n = nBase + waveN * 64 + j * 16 + idx16;
            const int part = n >> 10;
            const int rem = n & 1023;
            const int h = rem >> 6, d = rem & 63;
#pragma unroll
            for (int r = 0; r < 4; r++) {
                const int m = mBase + waveM * 64 + i * 16 + quad * 4 + r;
                const int bb = m >> 11, t = m & 2047;
                const size_t o = (size_t)part * QKV_STRIDE +
                                 (((size_t)(bb * Hc + h)) * Tc + t) * Dc + d;
                qkv[o] = __float2bfloat16(acc[i][j][r]);
            }
        }
    }
}

// ============ GEMM2 bf16 (R20): out(f32) = ao @ wbp^T, 128x128 tile =========
__global__ __launch_bounds__(256) void gemm_proj_bf16(
    const __hip_bfloat16* __restrict__ A,
    const __hip_bfloat16* __restrict__ W,
    float* __restrict__ out) {
    __shared__ __hip_bfloat16 As16[128 * 32];
    __shared__ __hip_bfloat16 Bs16[128 * 32];
    const int K = Cc;
    const int lane = threadIdx.x & 63;
    const int wave = threadIdx.x >> 6;
    const int waveM = wave >> 1, waveN = wave & 1;
    const int mBase = blockIdx.x * 128;
    const int nBase = blockIdx.y * 128;
    const int idx16 = lane & 15;
    const int quad = lane >> 4;
    const int aRow = lane >> 2, aPos = lane & 3;

    floatx4 acc[4][4] = {};

    for (int k0 = 0; k0 < K; k0 += 32) {
        __syncthreads();
#pragma unroll
        for (int s = 0; s < 2; s++) {
            const int r0 = wave * 32 + s * 16;
            const int row = r0 + aRow;
            const int cg = aPos ^ (row & 3);
            gl2lds16(A + (size_t)(mBase + row) * K + k0 + cg * 8, &As16[r0 * 32]);
            gl2lds16(W + (size_t)(nBase + row) * K + k0 + cg * 8, &Bs16[r0 * 32]);
        }
        __syncthreads();

        bf16x8 af[4], bfr[4];
#pragma unroll
        for (int i = 0; i < 4; i++) {
            const int rr = waveM * 64 + i * 16 + idx16;
            af[i] = *(const bf16x8*)&As16[rr * 32 + ((quad ^ (rr & 3)) * 8)];
        }
#pragma unroll
        for (int j = 0; j < 4; j++) {
            const int rr = waveN * 64 + j * 16 + idx16;
            bfr[j] = *(const bf16x8*)&Bs16[rr * 32 + ((quad ^ (rr & 3)) * 8)];
        }
#pragma unroll
        for (int i = 0; i < 4; i++)
#pragma unroll
            for (int j = 0; j < 4; j++)
                acc[i][j] = MFMA16(af[i], bfr[j], acc[i][j]);
    }

#pragma unroll
    for (int i = 0; i < 4; i++) {
#pragma unroll
        for (int j = 0; j < 4; j++) {
            const int n = nBase + waveN * 64 + j * 16 + idx16;
#pragma unroll
            for (int r = 0; r < 4; r++) {
                const int m = mBase + waveM * 64 + i * 16 + quad * 4 + r;
                out[(size_t)m * Cc + n] = acc[i][j][r];
            }
        }
    }
}

// ================= V transpose (unchanged): [b,h,t,d] -> [b,h,d,t] ==========
__global__ __launch_bounds__(256) void transpose_v(
    const __hip_bfloat16* __restrict__ v,
    __hip_bfloat16* __restrict__ vt) {
    __shared__ unsigned short tile[64][65];
    const int t0 = blockIdx.x * 64;
    const int h = blockIdx.y, b = blockIdx.z;
    const size_t base = ((size_t)(b * Hc + h)) * Tc * Dc;
    const unsigned short* vp = (const unsigned short*)v + base;
    unsigned short* vtp = (unsigned short*)vt + base;

    for (int e = threadIdx.x; e < 4096; e += 256) {
        const int tl = e >> 6, d = e & 63;
        tile[tl][d] = vp[(size_t)(t0 + tl) * Dc + d];
    }
    __syncthreads();
    for (int e = threadIdx.x; e < 4096; e += 256) {
        const int d = e >> 6, tl = e & 63;
        vtp[(size_t)d * Tc + t0 + tl] = tile[tl][d];
    }
}

// ================= Flash attention v11: folded, permlane softmax ============
// Block = (p, h, b), 512 threads. Fold schedule identical to R17 (17 steps).
// Per wave-tile (32 q x 64 keys): S^T = mfma32(K,Q) chained over d (4 ops/kb)
// -> exp2+mask in-reg -> pk2 -> 4x permlane32_swap builds PV A-frag words
// in place -> O += mfma32(P, V). q = qBase + (lane&31); S/O row formula
// (reg&3)+8*(reg>>2)+4*(lane>>5) [m74/m101]. LDS = 64KB staging only.
__global__ __launch_bounds__(512) void attn_fold(
    const __hip_bfloat16* __restrict__ qkv,
    const __hip_bfloat16* __restrict__ vt,
    __hip_bfloat16* __restrict__ aout) {
    __shared__ floatx4 smem4[4096];                          // 64KB
    char* const smem = (char*)smem4;
    __hip_bfloat16* const kA = (__hip_bfloat16*)smem;        // [2][4096]
    __hip_bfloat16* const vA = kA + 8192;
    __hip_bfloat16* const kB = vA + 8192;
    __hip_bfloat16* const vB = kB + 8192;
    float* const comb = (float*)smem;                        // post-loop alias

    const int lane = threadIdx.x & 63;
    const int wave = threadIdx.x >> 6;            // 0..7
    const int c31 = lane & 31;
    const int hw = lane >> 5;
    const int p = blockIdx.x;                     // 0..7
    const int h = blockIdx.y;
    const int b = blockIdx.z;
    const int H = 15 - p, L = p;
    const int lightEnd = 2 * p + 2;
    const int w3 = wave & 3;

    const size_t headOff = ((size_t)(b * Hc + h)) * Tc * Dc;
    const __hip_bfloat16* qp = qkv + headOff;
    const __hip_bfloat16* kp = qkv + QKV_STRIDE + headOff;
    const __hip_bfloat16* vtp = vt + headOff;     // [d][t] within head

    int qB = ((wave < 4) ? H : L) * 128 + w3 * 32;
    int qtw = (qB + 31) >> 6;
    int qMax = qB + 31;
    int qg = qB + c31;                            // this lane's q row

    bf16x8 qf0, qf1, qf2, qf3;                    // Q[qg][hw*8 + 16*j ..+8]
    auto loadQ = [&]() {
        const __hip_bfloat16* qr = qp + (size_t)qg * Dc + hw * 8;
        qf0 = load8(qr);
        qf1 = load8(qr + 16);
        qf2 = load8(qr + 32);
        qf3 = load8(qr + 48);
    };
    loadQ();

    f32x16 O0 = {}, O1 = {};                      // O[q rows][d 0..31 / 32..63]
    float lacc = 0.f;

    auto stageA = [&](int kt, int buf) {
        const int keyBase = kt * 64;
#pragma unroll
        for (int s = 0; s < 2; s++) {
            const int blk = w3 * 2 + s;
            const int row = blk * 8 + (lane >> 3);
            const int g = (lane & 7) ^ (row & 7);
            gl2lds16(kp + (size_t)(keyBase + row) * Dc + g * 8,
                     kA + buf * 4096 + blk * 512);
            gl2lds16(vtp + (size_t)row * Tc + keyBase + g * 8,
                     vA + buf * 4096 + blk * 512);
        }
    };
    auto stageB = [&](int kt, int buf) {
        const int keyBase = kt * 64;
#pragma unroll
        for (int s = 0; s < 2; s++) {
            const int blk = w3 * 2 + s;
            const int row = blk * 8 + (lane >> 3);
            const int g = (lane & 7) ^ (row & 7);
            gl2lds16(kp + (size_t)(keyBase + row) * Dc + g * 8,
                     kB + buf * 4096 + blk * 512);
            gl2lds16(vtp + (size_t)row * Tc + keyBase + g * 8,
                     vB + buf * 4096 + blk * 512);
        }
    };

    // per-tile: S^T -> in-reg P -> O += P V   (kb = 32-key half-tile)
    auto computeTile = [&](const __hip_bfloat16* kS, const __hip_bfloat16* vS,
                           int keyBase) {
#pragma unroll
        for (int kb = 0; kb < 2; kb++) {
            if (keyBase + kb * 32 <= qMax) {      // wave-uniform causal skip
                // --- S^T = K Q^T over d=64 (4 chained 32x32x16) ---
                const int kr = kb * 32 + c31;
                const int m8 = kr & 7;
                f32x16 S = {};
                S = MFMA32(load8(&kS[kr * 64 + (((0 + hw) ^ m8) * 8)]), qf0, S);
                S = MFMA32(load8(&kS[kr * 64 + (((2 + hw) ^ m8) * 8)]), qf1, S);
                S = MFMA32(load8(&kS[kr * 64 + (((4 + hw) ^ m8) * 8)]), qf2, S);
                S = MFMA32(load8(&kS[kr * 64 + (((6 + hw) ^ m8) * 8)]), qf3, S);

                // --- exp2 + mask + l + pack (w[i] = adjacent-key pairs) ---
                unsigned w[8];
#pragma unroll
                for (int r = 0; r < 16; r += 2) {
                    const int key0 = keyBase + kb * 32 +
                                     (r & 3) + 8 * (r >> 2) + 4 * hw;
                    float p0 = EXP2F(S[r] * KSL2E);
                    p0 = (key0 > qg) ? 0.f : p0;
                    float p1 = EXP2F(S[r + 1] * KSL2E);
                    p1 = (key0 + 1 > qg) ? 0.f : p1;
                    lacc += p0 + p1;
                    w[r >> 1] = pk2(p0, p1);
                }
                // lane(c31,hw) holds key-pairs:
                //  w0=(4hw+0,1) w1=(4hw+2,3) w2=(4hw+8,9) w3=(4hw+10,11)
                //  w4=(4hw+16,17) w5=(4hw+18,19) w6=(4hw+24,25) w7=(4hw+26,27)
                // Target word j of A-frag = keys (8hw+2j, 8hw+2j+1).
                // pl32swap(a,b): a.upper <-> b.lower (proven by R18/R19 diff):
                //   swap(w0,w2): w0 -> (own (0,1) | w2.lower (8,9))   = word0
                //                w2 -> (w0.upper (4,5) | own (12,13)) = word2
                pl32swap(w[0], w[2]);
                pl32swap(w[1], w[3]);
                pl32swap(w[4], w[6]);
                pl32swap(w[5], w[7]);
                const bf16x8 pA0 = mk8(w[0], w[1], w[2], w[3]); // keys 0..15
                const bf16x8 pA1 = mk8(w[4], w[5], w[6], w[7]); // keys 16..31

                // --- O += P V (V^T rows from LDS) ---
                {
                    const int vr = c31;                     // d 0..31
                    const int vm = vr & 7;
                    const bf16x8 vf0 = load8(&vS[vr * 64 + (((kb * 4 + hw) ^ vm) * 8)]);
                    const bf16x8 vf1 = load8(&vS[vr * 64 + (((kb * 4 + 2 + hw) ^ vm) * 8)]);
                    O0 = MFMA32(pA0, vf0, O0);
                    O0 = MFMA32(pA1, vf1, O0);
                }
                {
                    const int vr = 32 + c31;                // d 32..63
                    const int vm = vr & 7;
                    const bf16x8 vf0 = load8(&vS[vr * 64 + (((kb * 4 + hw) ^ vm) * 8)]);
                    const bf16x8 vf1 = load8(&vS[vr * 64 + (((kb * 4 + 2 + hw) ^ vm) * 8)]);
                    O1 = MFMA32(pA0, vf0, O1);
                    O1 = MFMA32(pA1, vf1, O1);
                }
            }
        }
    };

    // normalize + store O at q-base qB_ given combined ltot (valid all lanes)
    auto outStore = [&](int qB_, float ltot) {
#pragma unroll
        for (int r = 0; r < 16; r++) {
            const int qrl = (r & 3) + 8 * (r >> 2) + 4 * hw;
            const float lr = __shfl(ltot, qrl, 64);
            const float inv = 1.0f / lr;
            const size_t rowOff = ((size_t)(b * Tc + qB_ + qrl)) * Cc + h * 64;
            aout[rowOff + c31] = __float2bfloat16(O0[r] * inv);
            aout[rowOff + 32 + c31] = __float2bfloat16(O1[r] * inv);
        }
    };

    if (wave < 4) stageA(0, 0);

    for (int i = 0; i < 17; i++) {
        __syncthreads();                          // step-i buffers staged
        if (i < 16) {
            if (wave < 4) stageA(i + 1, (i + 1) & 1);
            else if (i + 1 >= lightEnd) stageB(i + 16 - 2 * p, (i + 1) & 1);
        }
        if (wave >= 4 && i == lightEnd) {
            // store light output, switch to heavy rows
            outStore(qB, lacc + __shfl_xor(lacc, 32, 64));
#pragma unroll
            for (int r = 0; r < 16; r++) { O0[r] = 0.f; O1[r] = 0.f; }
            lacc = 0.f;
            qB = H * 128 + w3 * 32;
            qtw = (qB + 31) >> 6;
            qMax = qB + 31;
            qg = qB + c31;
            loadQ();
        }
        if (wave < 4) {
            computeTile(kA + (i & 1) * 4096, vA + (i & 1) * 4096, i * 64);
        } else if (i < lightEnd) {
            if (i <= qtw)
                computeTile(kA + (i & 1) * 4096, vA + (i & 1) * 4096, i * 64);
        } else {
            const int kt = i + 15 - 2 * p;
            if (kt <= qtw)
                computeTile(kB + (i & 1) * 4096, vB + (i & 1) * 4096, kt * 64);
        }
        __syncthreads();                          // done reading step-i buffers
    }

    // --- combine heavy partials: B waves -> LDS (dead staging) -> A waves ---
    const float ltotOwn = lacc + __shfl_xor(lacc, 32, 64);
    if (wave >= 4) {
        float* c = comb + (size_t)(wave - 4) * 2112;
#pragma unroll
        for (int r = 0; r < 16; r++) {
            c[r * 64 + lane] = O0[r];
            c[(16 + r) * 64 + lane] = O1[r];
        }
        c[2048 + lane] = ltotOwn;
    }
    __syncthreads();
    if (wave < 4) {
        float* c = comb + (size_t)wave * 2112;
#pragma unroll
        for (int r = 0; r < 16; r++) {
            O0[r] += c[r * 64 + lane];
            O1[r] += c[(16 + r) * 64 + lane];
        }
        outStore(qB, ltotOwn + c[2048 + lane]);
    }
}

// ======== Fallback f32-staging GEMMs (used only if ws too small) ============
__global__ __launch_bounds__(256) void gemm_qkv(
    const float* __restrict__ A,
    const float* __restrict__ W,
    __hip_bfloat16* __restrict__ qkv) {
    __shared__ float As[128 * 32];
    __shared__ float Bs[128 * 32];
    const int K = Cc;
    const int lane = threadIdx.x & 63;
    const int wave = threadIdx.x >> 6;
    const int waveM = wave >> 1, waveN = wave & 1;
    const int mBase = blockIdx.x * 128;
    const int nBase = blockIdx.y * 128;
    const int idx16 = lane & 15;
    const int quad = lane >> 4;
    const int ldRow = lane >> 3;
    const int ldPos = lane & 7;

    floatx4 acc[4][4] = {};

    for (int k0 = 0; k0 < K; k0 += 32) {
        __syncthreads();
#pragma unroll
        for (int s = 0; s < 4; s++) {
            const int r0 = wave * 32 + s * 8;
            const int row = r0 + ldRow;
            const int cg = ldPos ^ (row & 7);
            gl2lds16(A + (size_t)(mBase + row) * K + k0 + cg * 4, &As[r0 * 32]);
            gl2lds16(W + (size_t)(nBase + row) * K + k0 + cg * 4, &Bs[r0 * 32]);
        }
        __syncthreads();

        bf16x8 af[4], bfr[4];
#pragma unroll
        for (int i = 0; i < 4; i++) {
            const int rr = waveM * 64 + i * 16 + idx16;
            const floatx4 a0 = *(const floatx4*)&As[rr * 32 + (((quad * 2) ^ (rr & 7)) * 4)];
            const floatx4 a1 = *(const floatx4*)&As[rr * 32 + (((quad * 2 + 1) ^ (rr & 7)) * 4)];
            af[i] = pack8(a0, a1);
        }
#pragma unroll
        for (int j = 0; j < 4; j++) {
            const int rr = waveN * 64 + j * 16 + idx16;
            const floatx4 b0 = *(const floatx4*)&Bs[rr * 32 + (((quad * 2) ^ (rr & 7)) * 4)];
            const floatx4 b1 = *(const floatx4*)&Bs[rr * 32 + (((quad * 2 + 1) ^ (rr & 7)) * 4)];
            bfr[j] = pack8(b0, b1);
        }
#pragma unroll
        for (int i = 0; i < 4; i++)
#pragma unroll
            for (int j = 0; j < 4; j++)
                acc[i][j] = MFMA16(af[i], bfr[j], acc[i][j]);
    }

#pragma unroll
    for (int i = 0; i < 4; i++) {
#pragma unroll
        for (int j = 0; j < 4; j++) {
            const int n = nBase + waveN * 64 + j * 16 + idx16;
            const int part = n >> 10;
            const int rem = n & 1023;
            const int h = rem >> 6, d = rem & 63;
#pragma unroll
            for (int r = 0; r < 4; r++) {
                const int m = mBase + waveM * 64 + i * 16 + quad * 4 + r;
                const int bb = m >> 11, t = m & 2047;
                const size_t o = (size_t)part * QKV_STRIDE +
                                 (((size_t)(bb * Hc + h)) * Tc + t) * Dc + d;
                qkv[o] = __float2bfloat16(acc[i][j][r]);
            }
        }
    }
}

__global__ __launch_bounds__(256) void gemm_proj(
    const __hip_bfloat16* __restrict__ A,
    const float* __restrict__ W,
    float* __restrict__ out) {
    __shared__ __hip_bfloat16 As16[128 * 32];
    __shared__ float Ws[64 * 32];
    const int K = Cc;
    const int lane = threadIdx.x & 63;
    const int wave = threadIdx.x >> 6;
    const int waveM = wave >> 1, waveN = wave & 1;
    const int mBase = blockIdx.x * 128;
    const int nBase = blockIdx.y * 64;
    const int idx16 = lane & 15;
    const int quad = lane >> 4;
    const int aRow = lane >> 2, aPos = lane & 3;
    const int wRow = lane >> 3, wPos = lane & 7;

    floatx4 acc[4][2] = {};

    for (int k0 = 0; k0 < K; k0 += 32) {
        __syncthreads();
#pragma unroll
        for (int s = 0; s < 2; s++) {
            {
                const int r0 = wave * 32 + s * 16;
                const int row = r0 + aRow;
                const int cg = aPos ^ (row & 3);
                gl2lds16(A + (size_t)(mBase + row) * K + k0 + cg * 8, &As16[r0 * 32]);
            }
            {
                const int r0 = wave * 16 + s * 8;
                const int row = r0 + wRow;
                const int cg = wPos ^ (row & 7);
                gl2lds16(W + (size_t)(nBase + row) * K + k0 + cg * 4, &Ws[r0 * 32]);
            }
        }
        __syncthreads();

        bf16x8 af[4], bfr[2];
#pragma unroll
        for (int i = 0; i < 4; i++) {
            const int rr = waveM * 64 + i * 16 + idx16;
            af[i] = *(const bf16x8*)&As16[rr * 32 + ((quad ^ (rr & 3)) * 8)];
        }
#pragma unroll
        for (int j = 0; j < 2; j++) {
            const int rr = waveN * 32 + j * 16 + idx16;
            const floatx4 b0 = *(const floatx4*)&Ws[rr * 32 + (((quad * 2) ^ (rr & 7)) * 4)];
            const floatx4 b1 = *(const floatx4*)&Ws[rr * 32 + (((quad * 2 + 1) ^ (rr & 7)) * 4)];
            bfr[j] = pack8(b0, b1);
        }
#pragma unroll
        for (int i = 0; i < 4; i++)
#pragma unroll
            for (int j = 0; j < 2; j++)
                acc[i][j] = MFMA16(af[i], bfr[j], acc[i][j]);
    }

#pragma unroll
    for (int i = 0; i < 4; i++) {
#pragma unroll
        for (int j = 0; j < 2; j++) {
            const int n = nBase + waveN * 32 + j * 16 + idx16;
#pragma unroll
            for (int r = 0; r < 4; r++) {
                const int m = mBase + waveM * 64 + i * 16 + quad * 4 + r;
                out[(size_t)m * Cc + n] = acc[i][j][r];
            }
        }
    }
}

extern "C" void kernel_launch(void* const* d_in, const int* in_sizes, int n_in,
                              void* d_out, int out_size, void* d_ws, size_t ws_size,
                              hipStream_t stream) {
    const float* x = nullptr;
    const float* w_qkv = nullptr;
    const float* w_proj = nullptr;
    for (int i = 0; i < n_in; i++) {
        if (in_sizes[i] == 4194304) x = (const float*)d_in[i];
        else if (in_sizes[i] == 3145728) w_qkv = (const float*)d_in[i];
        else if (in_sizes[i] == 1048576) w_proj = (const float*)d_in[i];
    }
    float* out = (float*)d_out;

    __hip_bfloat16* qkv = (__hip_bfloat16*)d_ws;        // q[4M] k[4M] v[4M]
    __hip_bfloat16* vbuf = qkv + 2 * QKV_STRIDE;        // v slot; becomes ao
    __hip_bfloat16* vt = qkv + 3 * QKV_STRIDE;          // 4M elems
    __hip_bfloat16* ao = vbuf;                          // attn out over dead v

    // bf16-input staging region after qkv+vt (8*QKV_STRIDE bytes = 32MB off)
    const size_t CVT_OFF = 8 * QKV_STRIDE;              // bytes
    const size_t NEED = CVT_OFF + (4194304 + 3145728) * sizeof(__hip_bfloat16);

    if (ws_size >= NEED) {
        __hip_bfloat16* xb = (__hip_bfloat16*)((char*)d_ws + CVT_OFF); // 8MB
        __hip_bfloat16* wbq = xb + 4194304;                            // 6MB
        __hip_bfloat16* wbp = qkv;    // q region, dead after attn

        cvt_bf16<<<dim3(4194304 / 8 / 256), 256, 0, stream>>>(x, xb, 4194304 / 8);
        cvt_bf16<<<dim3(3145728 / 8 / 256), 256, 0, stream>>>(w_qkv, wbq, 3145728 / 8);
        gemm_qkv_bf16<<<dim3(4096 / 128, 3072 / 128), 256, 0, stream>>>(xb, wbq, qkv);
        transpose_v<<<dim3(Tc / 64, Hc, Bc), 256, 0, stream>>>(vbuf, vt);
        attn_fold<<<dim3(8, Hc, Bc), 512, 0, stream>>>(qkv, vt, ao);
        cvt_bf16<<<dim3(1048576 / 8 / 256), 256, 0, stream>>>(w_proj, wbp, 1048576 / 8);
        gemm_proj_bf16<<<dim3(4096 / 128, 1024 / 128), 256, 0, stream>>>(ao, wbp, out);
    } else {
        gemm_qkv<<<dim3(4096 / 128, 3072 / 128), 256, 0, stream>>>(x, w_qkv, qkv);
        transpose_v<<<dim3(Tc / 64, Hc, Bc), 256, 0, stream>>>(vbuf, vt);
        attn_fold<<<dim3(8, Hc, Bc), 512, 0, stream>>>(qkv, vt, ao);
        gemm_proj<<<dim3(4096 / 128, 1024 / 64), 256, 0, stream>>>(ao, w_proj, out);
    }
}

// Round 12
// 181.052 us; speedup vs baseline: 1.0382x; 1.0382x over previous
//
#include <hip/hip_runtime.h>
#include <hip/hip_bf16.h>

// ROUND 21: (1) attn: single barrier per step — the old bottom barrier was
// back-to-back with the next top barrier (nothing between), so one barrier
// provides the same ordering (reads(i) < barrier(i+1) < stage writes into
// buf(i&1)); +1 barrier post-loop protects comb smem reuse. 34 -> 18.
// (2) attn: mask-free fast path — only the single diagonal tile per wave
// phase (keyBase+63 > qB) needs the causal cndmask; below-diagonal tiles
// skip 32 cndmask + 32 iadd (wave-uniform branch).
// (3) gemm_proj reverted to R19 128x64 (R20's 128x128 = 256 blocks = 1
// blk/CU occupancy regression, +6us); gemm_qkv gets bijective XCD swizzle
// (768%8==0) for W-panel L2 locality (T1).
// attn math otherwise identical to R20 (passing, permlane semantics proven).

typedef __attribute__((ext_vector_type(8))) short bf16x8;
typedef __attribute__((ext_vector_type(4))) short bf16x4;
typedef __attribute__((ext_vector_type(4))) float floatx4;
typedef __attribute__((ext_vector_type(16))) float f32x16;

#define MFMA16(a, b, c) __builtin_amdgcn_mfma_f32_16x16x32_bf16((a), (b), (c), 0, 0, 0)
#define MFMA32(a, b, c) __builtin_amdgcn_mfma_f32_32x32x16_bf16((a), (b), (c), 0, 0, 0)

#if __has_builtin(__builtin_amdgcn_exp2f)
#define EXP2F(x) __builtin_amdgcn_exp2f(x)
#else
#define EXP2F(x) exp2f(x)
#endif

static constexpr int Bc = 2, Tc = 2048, Cc = 1024, Hc = 16, Dc = 64;
static constexpr size_t QKV_STRIDE = (size_t)Bc * Hc * Tc * Dc; // 4194304
static constexpr float KSL2E = 0.125f * 1.44269504088896f; // scale * log2(e)

__device__ __forceinline__ bf16x8 load8(const __hip_bfloat16* p) {
    return *(const bf16x8*)p;
}

__device__ __forceinline__ short f2b(float x) {
    union { __hip_bfloat16 h; short s; } u;
    u.h = __float2bfloat16(x);
    return u.s;
}

__device__ __forceinline__ bf16x8 pack8(floatx4 a, floatx4 b) {
    bf16x8 r;
    r[0] = f2b(a[0]); r[1] = f2b(a[1]); r[2] = f2b(a[2]); r[3] = f2b(a[3]);
    r[4] = f2b(b[0]); r[5] = f2b(b[1]); r[6] = f2b(b[2]); r[7] = f2b(b[3]);
    return r;
}

// pack 2 f32 -> u32 of 2 bf16 (lo = a, hi = b); compiler emits cvt_pk
__device__ __forceinline__ unsigned pk2(float a, float b) {
    return (unsigned)(unsigned short)f2b(a) |
           ((unsigned)(unsigned short)f2b(b) << 16);
}

// v_permlane32_swap_b32 a, b: a.upper-half <-> b.lower-half (proven R18/R19)
__device__ __forceinline__ void pl32swap(unsigned& a, unsigned& b) {
    asm volatile("v_permlane32_swap_b32 %0, %1" : "+v"(a), "+v"(b));
}

__device__ __forceinline__ bf16x8 mk8(unsigned a, unsigned b, unsigned c, unsigned d) {
    union { unsigned u[4]; bf16x8 v; } x;
    x.u[0] = a; x.u[1] = b; x.u[2] = c; x.u[3] = d;
    return x.v;
}

__device__ __forceinline__ void gl2lds16(const void* g, void* l) {
    __builtin_amdgcn_global_load_lds(
        (const __attribute__((address_space(1))) void*)g,
        (__attribute__((address_space(3))) void*)l, 16, 0, 0);
}

// ================= f32 -> bf16 bulk convert (8 elems/thread) ================
__global__ __launch_bounds__(256) void cvt_bf16(
    const float* __restrict__ in, __hip_bfloat16* __restrict__ out, int n8) {
    const int i = blockIdx.x * 256 + threadIdx.x;
    if (i < n8) {
        const floatx4 a = *(const floatx4*)&in[(size_t)i * 8];
        const floatx4 b = *(const floatx4*)&in[(size_t)i * 8 + 4];
        *(bf16x8*)&out[(size_t)i * 8] = pack8(a, b);
    }
}

// ================= GEMM1 bf16: qkv = xb @ wb^T (+XCD swizzle) ===============
__global__ __launch_bounds__(256) void gemm_qkv_bf16(
    const __hip_bfloat16* __restrict__ A,
    const __hip_bfloat16* __restrict__ W,
    __hip_bfloat16* __restrict__ qkv) {
    __shared__ __hip_bfloat16 As16[128 * 32];
    __shared__ __hip_bfloat16 Bs16[128 * 32];
    const int K = Cc;
    const int lane = threadIdx.x & 63;
    const int wave = threadIdx.x >> 6;
    const int waveM = wave >> 1, waveN = wave & 1;
    // bijective XCD swizzle: nwg=768 (32x24), 768%8==0, chunk=96.
    // Consecutive swz share by (W panel) -> per-XCD L2 reuse.
    const int flat = blockIdx.y * 32 + blockIdx.x;
    const int swz = (flat & 7) * 96 + (flat >> 3);
    const int mBase = (swz & 31) * 128;
    const int nBase = (swz >> 5) * 128;
    const int idx16 = lane & 15;
    const int quad = lane >> 4;
    const int aRow = lane >> 2, aPos = lane & 3;

    floatx4 acc[4][4] = {};

    for (int k0 = 0; k0 < K; k0 += 32) {
        __syncthreads();
#pragma unroll
        for (int s = 0; s < 2; s++) {
            const int r0 = wave * 32 + s * 16;
            const int row = r0 + aRow;
            const int cg = aPos ^ (row & 3);
            gl2lds16(A + (size_t)(mBase + row) * K + k0 + cg * 8, &As16[r0 * 32]);
            gl2lds16(W + (size_t)(nBase + row) * K + k0 + cg * 8, &Bs16[r0 * 32]);
        }
        __syncthreads();

        bf16x8 af[4], bfr[4];
#pragma unroll
        for (int i = 0; i < 4; i++) {
            const int rr = waveM * 64 + i * 16 + idx16;
            af[i] = *(const bf16x8*)&As16[rr * 32 + ((quad ^ (rr & 3)) * 8)];
        }
#pragma unroll
        for (int j = 0; j < 4; j++) {
            const int rr = waveN * 64 + j * 16 + idx16;
            bfr[j] = *(const bf16x8*)&Bs16[rr * 32 + ((quad ^ (rr & 3)) * 8)];
        }
#pragma unroll
        for (int i = 0; i < 4; i++)
#pragma unroll
            for (int j = 0; j < 4; j++)
                acc[i][j] = MFMA16(af[i], bfr[j], acc[i][j]);
    }

#pragma unroll
    for (int i = 0; i < 4; i++) {
#pragma unroll
        for (int j = 0; j < 4; j++) {
            const int n = nBase + waveN * 64 + j * 16 + idx16;
            const int part = n >> 10;
            const int rem = n & 1023;
            const int h = rem >> 6, d = rem & 63;
#pragma unroll
            for (int r = 0; r < 4; r++) {
                const int m = mBase + waveM * 64 + i * 16 + quad * 4 + r;
                const int bb = m >> 11, t = m & 2047;
                const size_t o = (size_t)part * QKV_STRIDE +
                                 (((size_t)(bb * Hc + h)) * Tc + t) * Dc + d;
                qkv[o] = __float2bfloat16(acc[i][j][r]);
            }
        }
    }
}

// ============ GEMM2 bf16 (R19): out(f32) = ao @ wbp^T, 128x64 tile ==========
__global__ __launch_bounds__(256) void gemm_proj_bf16(
    const __hip_bfloat16* __restrict__ A,
    const __hip_bfloat16* __restrict__ W,
    float* __restrict__ out) {
    __shared__ __hip_bfloat16 As16[128 * 32];
    __shared__ __hip_bfloat16 Bs16[64 * 32];
    const int K = Cc;
    const int lane = threadIdx.x & 63;
    const int wave = threadIdx.x >> 6;
    const int waveM = wave >> 1, waveN = wave & 1;
    const int mBase = blockIdx.x * 128;
    const int nBase = blockIdx.y * 64;
    const int idx16 = lane & 15;
    const int quad = lane >> 4;
    const int aRow = lane >> 2, aPos = lane & 3;

    floatx4 acc[4][2] = {};

    for (int k0 = 0; k0 < K; k0 += 32) {
        __syncthreads();
#pragma unroll
        for (int s = 0; s < 2; s++) {
            const int r0 = wave * 32 + s * 16;
            const int row = r0 + aRow;
            const int cg = aPos ^ (row & 3);
            gl2lds16(A + (size_t)(mBase + row) * K + k0 + cg * 8, &As16[r0 * 32]);
        }
        {
            const int r0 = wave * 16;
            const int row = r0 + aRow;
            const int cg = aPos ^ (row & 3);
            gl2lds16(W + (size_t)(nBase + row) * K + k0 + cg * 8, &Bs16[r0 * 32]);
        }
        __syncthreads();

        bf16x8 af[4], bfr[2];
#pragma unroll
        for (int i = 0; i < 4; i++) {
            const int rr = waveM * 64 + i * 16 + idx16;
            af[i] = *(const bf16x8*)&As16[rr * 32 + ((quad ^ (rr & 3)) * 8)];
        }
#pragma unroll
        for (int j = 0; j < 2; j++) {
            const int rr = waveN * 32 + j * 16 + idx16;
            bfr[j] = *(const bf16x8*)&Bs16[rr * 32 + ((quad ^ (rr & 3)) * 8)];
        }
#pragma unroll
        for (int i = 0; i < 4; i++)
#pragma unroll
            for (int j = 0; j < 2; j++)
                acc[i][j] = MFMA16(af[i], bfr[j], acc[i][j]);
    }

#pragma unroll
    for (int i = 0; i < 4; i++) {
#pragma unroll
        for (int j = 0; j < 2; j++) {
            const int n = nBase + waveN * 32 + j * 16 + idx16;
#pragma unroll
            for (int r = 0; r < 4; r++) {
                const int m = mBase + waveM * 64 + i * 16 + quad * 4 + r;
                out[(size_t)m * Cc + n] = acc[i][j][r];
            }
        }
    }
}

// ================= V transpose (unchanged): [b,h,t,d] -> [b,h,d,t] ==========
__global__ __launch_bounds__(256) void transpose_v(
    const __hip_bfloat16* __restrict__ v,
    __hip_bfloat16* __restrict__ vt) {
    __shared__ unsigned short tile[64][65];
    const int t0 = blockIdx.x * 64;
    const int h = blockIdx.y, b = blockIdx.z;
    const size_t base = ((size_t)(b * Hc + h)) * Tc * Dc;
    const unsigned short* vp = (const unsigned short*)v + base;
    unsigned short* vtp = (unsigned short*)vt + base;

    for (int e = threadIdx.x; e < 4096; e += 256) {
        const int tl = e >> 6, d = e & 63;
        tile[tl][d] = vp[(size_t)(t0 + tl) * Dc + d];
    }
    __syncthreads();
    for (int e = threadIdx.x; e < 4096; e += 256) {
        const int d = e >> 6, tl = e & 63;
        vtp[(size_t)d * Tc + t0 + tl] = tile[tl][d];
    }
}

// ================= Flash attention v12: folded, 1 barrier/step ==============
// Block = (p, h, b), 512 threads. Fold schedule = R17 (17 uniform steps).
// Per wave-tile (32 q x 64 keys): S^T = mfma32(K,Q) chained over d (4 ops/kb)
// -> exp2 (+mask only on the diagonal tile) -> pk2 -> 4x permlane32_swap
// -> O += mfma32(P, V). One __syncthreads per step (see R21 header note).
__global__ __launch_bounds__(512) void attn_fold(
    const __hip_bfloat16* __restrict__ qkv,
    const __hip_bfloat16* __restrict__ vt,
    __hip_bfloat16* __restrict__ aout) {
    __shared__ floatx4 smem4[4096];                          // 64KB
    char* const smem = (char*)smem4;
    __hip_bfloat16* const kA = (__hip_bfloat16*)smem;        // [2][4096]
    __hip_bfloat16* const vA = kA + 8192;
    __hip_bfloat16* const kB = vA + 8192;
    __hip_bfloat16* const vB = kB + 8192;
    float* const comb = (float*)smem;                        // post-loop alias

    const int lane = threadIdx.x & 63;
    const int wave = threadIdx.x >> 6;            // 0..7
    const int c31 = lane & 31;
    const int hw = lane >> 5;
    const int p = blockIdx.x;                     // 0..7
    const int h = blockIdx.y;
    const int b = blockIdx.z;
    const int H = 15 - p, L = p;
    const int lightEnd = 2 * p + 2;
    const int w3 = wave & 3;

    const size_t headOff = ((size_t)(b * Hc + h)) * Tc * Dc;
    const __hip_bfloat16* qp = qkv + headOff;
    const __hip_bfloat16* kp = qkv + QKV_STRIDE + headOff;
    const __hip_bfloat16* vtp = vt + headOff;     // [d][t] within head

    int qB = ((wave < 4) ? H : L) * 128 + w3 * 32;
    int qtw = (qB + 31) >> 6;
    int qMax = qB + 31;
    int qg = qB + c31;                            // this lane's q row

    bf16x8 qf0, qf1, qf2, qf3;                    // Q[qg][hw*8 + 16*j ..+8]
    auto loadQ = [&]() {
        const __hip_bfloat16* qr = qp + (size_t)qg * Dc + hw * 8;
        qf0 = load8(qr);
        qf1 = load8(qr + 16);
        qf2 = load8(qr + 32);
        qf3 = load8(qr + 48);
    };
    loadQ();

    f32x16 O0 = {}, O1 = {};                      // O[q rows][d 0..31 / 32..63]
    float lacc = 0.f;

    auto stageA = [&](int kt, int buf) {
        const int keyBase = kt * 64;
#pragma unroll
        for (int s = 0; s < 2; s++) {
            const int blk = w3 * 2 + s;
            const int row = blk * 8 + (lane >> 3);
            const int g = (lane & 7) ^ (row & 7);
            gl2lds16(kp + (size_t)(keyBase + row) * Dc + g * 8,
                     kA + buf * 4096 + blk * 512);
            gl2lds16(vtp + (size_t)row * Tc + keyBase + g * 8,
                     vA + buf * 4096 + blk * 512);
        }
    };
    auto stageB = [&](int kt, int buf) {
        const int keyBase = kt * 64;
#pragma unroll
        for (int s = 0; s < 2; s++) {
            const int blk = w3 * 2 + s;
            const int row = blk * 8 + (lane >> 3);
            const int g = (lane & 7) ^ (row & 7);
            gl2lds16(kp + (size_t)(keyBase + row) * Dc + g * 8,
                     kB + buf * 4096 + blk * 512);
            gl2lds16(vtp + (size_t)row * Tc + keyBase + g * 8,
                     vB + buf * 4096 + blk * 512);
        }
    };

    // per-tile: S^T -> in-reg P -> O += P V   (kb = 32-key half-tile).
    // msk: only the diagonal tile (keyBase+63 > qB) needs the causal cndmask.
    auto computeTile = [&](const __hip_bfloat16* kS, const __hip_bfloat16* vS,
                           int keyBase, bool msk) {
#pragma unroll
        for (int kb = 0; kb < 2; kb++) {
            if (keyBase + kb * 32 <= qMax) {      // wave-uniform causal skip
                // --- S^T = K Q^T over d=64 (4 chained 32x32x16) ---
                const int kr = kb * 32 + c31;
                const int m8 = kr & 7;
                f32x16 S = {};
                S = MFMA32(load8(&kS[kr * 64 + (((0 + hw) ^ m8) * 8)]), qf0, S);
                S = MFMA32(load8(&kS[kr * 64 + (((2 + hw) ^ m8) * 8)]), qf1, S);
                S = MFMA32(load8(&kS[kr * 64 + (((4 + hw) ^ m8) * 8)]), qf2, S);
                S = MFMA32(load8(&kS[kr * 64 + (((6 + hw) ^ m8) * 8)]), qf3, S);

                // --- exp2 (+mask on diagonal tile) + l + pack ---
                unsigned w[8];
                if (msk) {
#pragma unroll
                    for (int r = 0; r < 16; r += 2) {
                        const int key0 = keyBase + kb * 32 +
                                         (r & 3) + 8 * (r >> 2) + 4 * hw;
                        float p0 = EXP2F(S[r] * KSL2E);
                        p0 = (key0 > qg) ? 0.f : p0;
                        float p1 = EXP2F(S[r + 1] * KSL2E);
                        p1 = (key0 + 1 > qg) ? 0.f : p1;
                        lacc += p0 + p1;
                        w[r >> 1] = pk2(p0, p1);
                    }
                } else {
#pragma unroll
                    for (int r = 0; r < 16; r += 2) {
                        const float p0 = EXP2F(S[r] * KSL2E);
                        const float p1 = EXP2F(S[r + 1] * KSL2E);
                        lacc += p0 + p1;
                        w[r >> 1] = pk2(p0, p1);
                    }
                }
                // pl32swap(a,b): a.upper <-> b.lower (proven R18/R19 diff)
                pl32swap(w[0], w[2]);
                pl32swap(w[1], w[3]);
                pl32swap(w[4], w[6]);
                pl32swap(w[5], w[7]);
                const bf16x8 pA0 = mk8(w[0], w[1], w[2], w[3]); // keys 0..15
                const bf16x8 pA1 = mk8(w[4], w[5], w[6], w[7]); // keys 16..31

                // --- O += P V (V^T rows from LDS) ---
                {
                    const int vr = c31;                     // d 0..31
                    const int vm = vr & 7;
                    const bf16x8 vf0 = load8(&vS[vr * 64 + (((kb * 4 + hw) ^ vm) * 8)]);
                    const bf16x8 vf1 = load8(&vS[vr * 64 + (((kb * 4 + 2 + hw) ^ vm) * 8)]);
                    O0 = MFMA32(pA0, vf0, O0);
                    O0 = MFMA32(pA1, vf1, O0);
                }
                {
                    const int vr = 32 + c31;                // d 32..63
                    const int vm = vr & 7;
                    const bf16x8 vf0 = load8(&vS[vr * 64 + (((kb * 4 + hw) ^ vm) * 8)]);
                    const bf16x8 vf1 = load8(&vS[vr * 64 + (((kb * 4 + 2 + hw) ^ vm) * 8)]);
                    O1 = MFMA32(pA0, vf0, O1);
                    O1 = MFMA32(pA1, vf1, O1);
                }
            }
        }
    };

    // normalize + store O at q-base qB_ given combined ltot (valid all lanes)
    auto outStore = [&](int qB_, float ltot) {
#pragma unroll
        for (int r = 0; r < 16; r++) {
            const int qrl = (r & 3) + 8 * (r >> 2) + 4 * hw;
            const float lr = __shfl(ltot, qrl, 64);
            const float inv = 1.0f / lr;
            const size_t rowOff = ((size_t)(b * Tc + qB_ + qrl)) * Cc + h * 64;
            aout[rowOff + c31] = __float2bfloat16(O0[r] * inv);
            aout[rowOff + 32 + c31] = __float2bfloat16(O1[r] * inv);
        }
    };

    if (wave < 4) stageA(0, 0);

    for (int i = 0; i < 17; i++) {
        __syncthreads();                          // single barrier per step:
        // reads(i-1) < this barrier < stage writes into buf((i+1)&1)
        if (i < 16) {
            if (wave < 4) stageA(i + 1, (i + 1) & 1);
            else if (i + 1 >= lightEnd) stageB(i + 16 - 2 * p, (i + 1) & 1);
        }
        if (wave >= 4 && i == lightEnd) {
            // store light output, switch to heavy rows
            outStore(qB, lacc + __shfl_xor(lacc, 32, 64));
#pragma unroll
            for (int r = 0; r < 16; r++) { O0[r] = 0.f; O1[r] = 0.f; }
            lacc = 0.f;
            qB = H * 128 + w3 * 32;
            qtw = (qB + 31) >> 6;
            qMax = qB + 31;
            qg = qB + c31;
            loadQ();
        }
        if (wave < 4) {
            computeTile(kA + (i & 1) * 4096, vA + (i & 1) * 4096, i * 64,
                        i * 64 + 63 > qB);
        } else if (i < lightEnd) {
            if (i <= qtw)
                computeTile(kA + (i & 1) * 4096, vA + (i & 1) * 4096, i * 64,
                            i * 64 + 63 > qB);
        } else {
            const int kt = i + 15 - 2 * p;
            if (kt <= qtw)
                computeTile(kB + (i & 1) * 4096, vB + (i & 1) * 4096, kt * 64,
                            kt * 64 + 63 > qB);
        }
        // (no bottom barrier — next iteration's top barrier orders buf reuse)
    }
    __syncthreads();   // last compute reads < comb writes (smem alias)

    // --- combine heavy partials: B waves -> LDS (dead staging) -> A waves ---
    const float ltotOwn = lacc + __shfl_xor(lacc, 32, 64);
    if (wave >= 4) {
        float* c = comb + (size_t)(wave - 4) * 2112;
#pragma unroll
        for (int r = 0; r < 16; r++) {
            c[r * 64 + lane] = O0[r];
            c[(16 + r) * 64 + lane] = O1[r];
        }
        c[2048 + lane] = ltotOwn;
    }
    __syncthreads();
    if (wave < 4) {
        float* c = comb + (size_t)wave * 2112;
#pragma unroll
        for (int r = 0; r < 16; r++) {
            O0[r] += c[r * 64 + lane];
            O1[r] += c[(16 + r) * 64 + lane];
        }
        outStore(qB, ltotOwn + c[2048 + lane]);
    }
}

// ======== Fallback f32-staging GEMMs (used only if ws too small) ============
__global__ __launch_bounds__(256) void gemm_qkv(
    const float* __restrict__ A,
    const float* __restrict__ W,
    __hip_bfloat16* __restrict__ qkv) {
    __shared__ float As[128 * 32];
    __shared__ float Bs[128 * 32];
    const int K = Cc;
    const int lane = threadIdx.x & 63;
    const int wave = threadIdx.x >> 6;
    const int waveM = wave >> 1, waveN = wave & 1;
    const int mBase = blockIdx.x * 128;
    const int nBase = blockIdx.y * 128;
    const int idx16 = lane & 15;
    const int quad = lane >> 4;
    const int ldRow = lane >> 3;
    const int ldPos = lane & 7;

    floatx4 acc[4][4] = {};

    for (int k0 = 0; k0 < K; k0 += 32) {
        __syncthreads();
#pragma unroll
        for (int s = 0; s < 4; s++) {
            const int r0 = wave * 32 + s * 8;
            const int row = r0 + ldRow;
            const int cg = ldPos ^ (row & 7);
            gl2lds16(A + (size_t)(mBase + row) * K + k0 + cg * 4, &As[r0 * 32]);
            gl2lds16(W + (size_t)(nBase + row) * K + k0 + cg * 4, &Bs[r0 * 32]);
        }
        __syncthreads();

        bf16x8 af[4], bfr[4];
#pragma unroll
        for (int i = 0; i < 4; i++) {
            const int rr = waveM * 64 + i * 16 + idx16;
            const floatx4 a0 = *(const floatx4*)&As[rr * 32 + (((quad * 2) ^ (rr & 7)) * 4)];
            const floatx4 a1 = *(const floatx4*)&As[rr * 32 + (((quad * 2 + 1) ^ (rr & 7)) * 4)];
            af[i] = pack8(a0, a1);
        }
#pragma unroll
        for (int j = 0; j < 4; j++) {
            const int rr = waveN * 64 + j * 16 + idx16;
            const floatx4 b0 = *(const floatx4*)&Bs[rr * 32 + (((quad * 2) ^ (rr & 7)) * 4)];
            const floatx4 b1 = *(const floatx4*)&Bs[rr * 32 + (((quad * 2 + 1) ^ (rr & 7)) * 4)];
            bfr[j] = pack8(b0, b1);
        }
#pragma unroll
        for (int i = 0; i < 4; i++)
#pragma unroll
            for (int j = 0; j < 4; j++)
                acc[i][j] = MFMA16(af[i], bfr[j], acc[i][j]);
    }

#pragma unroll
    for (int i = 0; i < 4; i++) {
#pragma unroll
        for (int j = 0; j < 4; j++) {
            const int n = nBase + waveN * 64 + j * 16 + idx16;
            const int part = n >> 10;
            const int rem = n & 1023;
            const int h = rem >> 6, d = rem & 63;
#pragma unroll
            for (int r = 0; r < 4; r++) {
                const int m = mBase + waveM * 64 + i * 16 + quad * 4 + r;
                const int bb = m >> 11, t = m & 2047;
                const size_t o = (size_t)part * QKV_STRIDE +
                                 (((size_t)(bb * Hc + h)) * Tc + t) * Dc + d;
                qkv[o] = __float2bfloat16(acc[i][j][r]);
            }
        }
    }
}

__global__ __launch_bounds__(256) void gemm_proj(
    const __hip_bfloat16* __restrict__ A,
    const float* __restrict__ W,
    float* __restrict__ out) {
    __shared__ __hip_bfloat16 As16[128 * 32];
    __shared__ float Ws[64 * 32];
    const int K = Cc;
    const int lane = threadIdx.x & 63;
    const int wave = threadIdx.x >> 6;
    const int waveM = wave >> 1, waveN = wave & 1;
    const int mBase = blockIdx.x * 128;
    const int nBase = blockIdx.y * 64;
    const int idx16 = lane & 15;
    const int quad = lane >> 4;
    const int aRow = lane >> 2, aPos = lane & 3;
    const int wRow = lane >> 3, wPos = lane & 7;

    floatx4 acc[4][2] = {};

    for (int k0 = 0; k0 < K; k0 += 32) {
        __syncthreads();
#pragma unroll
        for (int s = 0; s < 2; s++) {
            {
                const int r0 = wave * 32 + s * 16;
                const int row = r0 + aRow;
                const int cg = aPos ^ (row & 3);
                gl2lds16(A + (size_t)(mBase + row) * K + k0 + cg * 8, &As16[r0 * 32]);
            }
            {
                const int r0 = wave * 16 + s * 8;
                const int row = r0 + wRow;
                const int cg = wPos ^ (row & 7);
                gl2lds16(W + (size_t)(nBase + row) * K + k0 + cg * 4, &Ws[r0 * 32]);
            }
        }
        __syncthreads();

        bf16x8 af[4], bfr[2];
#pragma unroll
        for (int i = 0; i < 4; i++) {
            const int rr = waveM * 64 + i * 16 + idx16;
            af[i] = *(const bf16x8*)&As16[rr * 32 + ((quad ^ (rr & 3)) * 8)];
        }
#pragma unroll
        for (int j = 0; j < 2; j++) {
            const int rr = waveN * 32 + j * 16 + idx16;
            const floatx4 b0 = *(const floatx4*)&Ws[rr * 32 + (((quad * 2) ^ (rr & 7)) * 4)];
            const floatx4 b1 = *(const floatx4*)&Ws[rr * 32 + (((quad * 2 + 1) ^ (rr & 7)) * 4)];
            bfr[j] = pack8(b0, b1);
        }
#pragma unroll
        for (int i = 0; i < 4; i++)
#pragma unroll
            for (int j = 0; j < 2; j++)
                acc[i][j] = MFMA16(af[i], bfr[j], acc[i][j]);
    }

#pragma unroll
    for (int i = 0; i < 4; i++) {
#pragma unroll
        for (int j = 0; j < 2; j++) {
            const int n = nBase + waveN * 32 + j * 16 + idx16;
#pragma unroll
            for (int r = 0; r < 4; r++) {
                const int m = mBase + waveM * 64 + i * 16 + quad * 4 + r;
                out[(size_t)m * Cc + n] = acc[i][j][r];
            }
        }
    }
}

extern "C" void kernel_launch(void* const* d_in, const int* in_sizes, int n_in,
                              void* d_out, int out_size, void* d_ws, size_t ws_size,
                              hipStream_t stream) {
    const float* x = nullptr;
    const float* w_qkv = nullptr;
    const float* w_proj = nullptr;
    for (int i = 0; i < n_in; i++) {
        if (in_sizes[i] == 4194304) x = (const float*)d_in[i];
        else if (in_sizes[i] == 3145728) w_qkv = (const float*)d_in[i];
        else if (in_sizes[i] == 1048576) w_proj = (const float*)d_in[i];
    }
    float* out = (float*)d_out;

    __hip_bfloat16* qkv = (__hip_bfloat16*)d_ws;        // q[4M] k[4M] v[4M]
    __hip_bfloat16* vbuf = qkv + 2 * QKV_STRIDE;        // v slot; becomes ao
    __hip_bfloat16* vt = qkv + 3 * QKV_STRIDE;          // 4M elems
    __hip_bfloat16* ao = vbuf;                          // attn out over dead v

    // bf16-input staging region after qkv+vt (8*QKV_STRIDE bytes = 32MB off)
    const size_t CVT_OFF = 8 * QKV_STRIDE;              // bytes
    const size_t NEED = CVT_OFF + (4194304 + 3145728) * sizeof(__hip_bfloat16);

    if (ws_size >= NEED) {
        __hip_bfloat16* xb = (__hip_bfloat16*)((char*)d_ws + CVT_OFF); // 8MB
        __hip_bfloat16* wbq = xb + 4194304;                            // 6MB
        __hip_bfloat16* wbp = qkv;    // q region, dead after attn

        cvt_bf16<<<dim3(4194304 / 8 / 256), 256, 0, stream>>>(x, xb, 4194304 / 8);
        cvt_bf16<<<dim3(3145728 / 8 / 256), 256, 0, stream>>>(w_qkv, wbq, 3145728 / 8);
        gemm_qkv_bf16<<<dim3(4096 / 128, 3072 / 128), 256, 0, stream>>>(xb, wbq, qkv);
        transpose_v<<<dim3(Tc / 64, Hc, Bc), 256, 0, stream>>>(vbuf, vt);
        attn_fold<<<dim3(8, Hc, Bc), 512, 0, stream>>>(qkv, vt, ao);
        cvt_bf16<<<dim3(1048576 / 8 / 256), 256, 0, stream>>>(w_proj, wbp, 1048576 / 8);
        gemm_proj_bf16<<<dim3(4096 / 128, 1024 / 64), 256, 0, stream>>>(ao, wbp, out);
    } else {
        gemm_qkv<<<dim3(4096 / 128, 3072 / 128), 256, 0, stream>>>(x, w_qkv, qkv);
        transpose_v<<<dim3(Tc / 64, Hc, Bc), 256, 0, stream>>>(vbuf, vt);
        attn_fold<<<dim3(8, Hc, Bc), 512, 0, stream>>>(qkv, vt, ao);
        gemm_proj<<<dim3(4096 / 128, 1024 / 64), 256, 0, stream>>>(ao, w_proj, out);
    }
}